// Round 3
// baseline (1487.986 us; speedup 1.0000x reference)
//
#include <hip/hip_runtime.h>
#include <cstdint>

using u16 = unsigned short;
using u32 = unsigned int;

typedef __bf16 bf16x8 __attribute__((ext_vector_type(8)));
typedef float  floatx4 __attribute__((ext_vector_type(4)));

#define DEV static __device__ __forceinline__

// ---------- helpers ----------
DEV u16 f2bf(float f) {                 // f32 -> bf16 RNE
    u32 u = __float_as_uint(f);
    u += 0x7FFFu + ((u >> 16) & 1u);
    return (u16)(u >> 16);
}
DEV float bf2f(u16 v) { return __uint_as_float(((u32)v) << 16); }

DEV floatx4 mfma32(bf16x8 a, bf16x8 b, floatx4 c) {
    return __builtin_amdgcn_mfma_f32_16x16x32_bf16(a, b, c, 0, 0, 0);
}

DEV floatx4 fzero() { floatx4 z; z[0]=0.f; z[1]=0.f; z[2]=0.f; z[3]=0.f; return z; }

typedef __attribute__((address_space(3))) u32 as3_u32;
typedef __attribute__((address_space(1))) u32 as1_u32;

// async global->LDS, 16B per lane; LDS dest = wave-uniform base + lane*16.
DEV void async_ld16(const u16* g, u16* l) {
    __builtin_amdgcn_global_load_lds(
        (const as1_u32*)g, (as3_u32*)l, 16, 0, 0);
}

// ---------- weight transpose: W[K][N] f32 -> Wt[N][K] bf16 ----------
__global__ __launch_bounds__(256) void transpose_w(
    const float* __restrict__ W, u16* __restrict__ Wt, int K, int N)
{
    __shared__ float t[32][33];
    const int tx = threadIdx.x, ty = threadIdx.y;   // block 32x8
    const int gx = blockIdx.x * 32;                 // N dim
    const int gy = blockIdx.y * 32;                 // K dim
    #pragma unroll
    for (int i = 0; i < 4; ++i)
        t[ty + i*8][tx] = W[(size_t)(gy + ty + i*8) * N + gx + tx];
    __syncthreads();
    #pragma unroll
    for (int i = 0; i < 4; ++i)
        Wt[(size_t)(gx + ty + i*8) * K + gy + tx] = f2bf(t[tx][ty + i*8]);
}

// ---------- LayerNorm (wave per row, 4 rows/block), writes bf16 ----------
template<int MODE>
__global__ __launch_bounds__(256) void ln_kernel(
    const float* __restrict__ xp, const u16* __restrict__ xt2,
    const float* __restrict__ w, const float* __restrict__ b,
    u16* __restrict__ out, int nrows)
{
    const int row = blockIdx.x * 4 + (threadIdx.x >> 6);
    if (row >= nrows) return;
    const int lane = threadIdx.x & 63;
    float vals[12];
    if constexpr (MODE == 0) {
        const float* src = xp + (size_t)(row + row/3136 + 1) * 768;
        #pragma unroll
        for (int j = 0; j < 3; ++j) {
            float4 v = reinterpret_cast<const float4*>(src)[j*64 + lane];
            vals[j*4+0]=v.x; vals[j*4+1]=v.y; vals[j*4+2]=v.z; vals[j*4+3]=v.w;
        }
    } else {
        const int bt = row / 197;
        const int p  = row - bt * 197;
        const int b0 = bt >> 4, tt = bt & 15;
        if (p == 0) {
            const float* src = xp + (size_t)b0 * 3137 * 768;
            #pragma unroll
            for (int j = 0; j < 3; ++j) {
                float4 v = reinterpret_cast<const float4*>(src)[j*64 + lane];
                vals[j*4+0]=v.x; vals[j*4+1]=v.y; vals[j*4+2]=v.z; vals[j*4+3]=v.w;
            }
        } else {
            const u16* src = xt2 + (size_t)(b0*3136 + (p-1)*16 + tt) * 768;
            #pragma unroll
            for (int j = 0; j < 3; ++j) {
                uint2 q = reinterpret_cast<const uint2*>(src)[j*64 + lane];
                vals[j*4+0] = bf2f((u16)(q.x & 0xFFFF));
                vals[j*4+1] = bf2f((u16)(q.x >> 16));
                vals[j*4+2] = bf2f((u16)(q.y & 0xFFFF));
                vals[j*4+3] = bf2f((u16)(q.y >> 16));
            }
        }
    }
    float s = 0.f, ss = 0.f;
    #pragma unroll
    for (int e = 0; e < 12; ++e) { s += vals[e]; ss += vals[e]*vals[e]; }
    #pragma unroll
    for (int o = 32; o > 0; o >>= 1) { s += __shfl_xor(s, o); ss += __shfl_xor(ss, o); }
    const float mean = s * (1.f/768.f);
    const float var  = ss * (1.f/768.f) - mean*mean;
    const float rstd = rsqrtf(var + 1e-5f);
    #pragma unroll
    for (int j = 0; j < 3; ++j) {
        const int c4 = (j*64 + lane) * 4;
        union { u16 u[4]; uint2 q; } o;
        #pragma unroll
        for (int e = 0; e < 4; ++e)
            o.u[e] = f2bf((vals[j*4+e] - mean)*rstd*w[c4+e] + b[c4+e]);
        *reinterpret_cast<uint2*>(&out[(size_t)row*768 + c4]) = o.q;
    }
}

// ---------- combine: x_new = concat residuals (f32 -> d_out), then LN(n2) bf16 ----------
__global__ __launch_bounds__(256) void combine_ln2(
    const float* __restrict__ xp, const u16* __restrict__ xt2,
    const u16* __restrict__ rsb, const float* __restrict__ w, const float* __restrict__ b,
    float* __restrict__ xnew, u16* __restrict__ ln2, int nrows)
{
    const int row = blockIdx.x * 4 + (threadIdx.x >> 6);
    if (row >= nrows) return;
    const int lane = threadIdx.x & 63;
    const int b0 = row / 3137;
    const int j  = row - b0 * 3137;
    float vals[12];
    if (j == 0) {       // cls row: x[b,0] + mean_t rs[(b,t) seq, token 0]
        #pragma unroll
        for (int e = 0; e < 12; ++e) {
            const int c = e*64 + lane;
            float acc = 0.f;
            for (int t = 0; t < 16; ++t)
                acc += bf2f(rsb[(size_t)(b0*16 + t) * 197 * 768 + c]);
            vals[e] = xp[(size_t)row*768 + c] + acc * (1.f/16.f);
        }
    } else {
        const int n_idx = j - 1;
        const int hw = n_idx >> 4, tt = n_idx & 15;
        const u16* a  = xt2 + (size_t)(b0*3136 + n_idx) * 768;
        const u16* r2 = rsb + (size_t)((b0*16 + tt)*197 + 1 + hw) * 768;
        #pragma unroll
        for (int e = 0; e < 12; ++e) {
            const int c = e*64 + lane;
            vals[e] = bf2f(a[c]) + bf2f(r2[c]);
        }
    }
    float s = 0.f, ss = 0.f;
    #pragma unroll
    for (int e = 0; e < 12; ++e) { s += vals[e]; ss += vals[e]*vals[e]; }
    #pragma unroll
    for (int o = 32; o > 0; o >>= 1) { s += __shfl_xor(s, o); ss += __shfl_xor(ss, o); }
    const float mean = s * (1.f/768.f);
    const float var  = ss * (1.f/768.f) - mean*mean;
    const float rstd = rsqrtf(var + 1e-5f);
    #pragma unroll
    for (int e = 0; e < 12; ++e) {
        const int c = e*64 + lane;
        xnew[(size_t)row*768 + c] = vals[e];
        ln2[(size_t)row*768 + c]  = f2bf((vals[e] - mean)*rstd*w[c] + b[c]);
    }
}

// ============================================================================
// PERSISTENT GEMM, 256x256 tiles, BK=64, 8 waves (2Mx4N).
// Grid = 256 blocks; each block walks a contiguous tile range (n-fastest ->
// consecutive tiles share the A panel -> L2 reuse). The K-tile stream is
// CONTINUOUS across output tiles: uniform 4-phase/K-tile schedule, gate =
// vmcnt(6) once per K-tile. One pipeline fill per BLOCK.
//
// Region liveness per tile s (buffer d=s&1):  B.h0/B.h1 die at PH2 (last
// RD_B(d,1)); A.h0/A.h1 die at PH3 (last RD_A(d,1)).  Stage rotation
// (each issue >=1 barrier after the target region's last read):
//   PH1(s): (s+1).A1  -> buffer d^1, region dead since PH3(s-1)
//   PH3(s): (s+2).B0  -> buffer d,   B.h0 dead after PH2(s)
//   PH4(s): (s+2).B1 + (s+2).A0 -> buffer d, dead after PH2/PH3(s)
// Gate vmcnt(6) at PH4(s): trailing = PH3(s)2 + PH4(s)4 loads; everything
// through (s+1).A1 (issued PH1(s)) is forced complete -> tile s+1 readable.
// Issue->gate slack: A1=3, A0/B1=4, B0=5 phases.
// Tail: stages with sp>=s_hi clamp the SOURCE to the last real K-tile but
// keep the true-parity dest; they follow the same slot discipline, so the
// steady-state liveness proof covers them. Epilogue: register->global
// direct, no LDS, no barrier; overlaps in-flight prefetch. Final vmcnt(0)
// drains DMA before LDS is reallocated.
// XOR chunk swizzle: physical 16B-chunk p of row r holds logical p^(r&7);
// global source pre-swizzled, LDS dest lane-linear (gload_lds constraint).
// ============================================================================

#define BARX() do { __builtin_amdgcn_sched_barrier(0); asm volatile("" ::: "memory"); \
    __builtin_amdgcn_s_barrier(); asm volatile("" ::: "memory"); \
    __builtin_amdgcn_sched_barrier(0); } while(0)
#define WAITL() do { asm volatile("s_waitcnt lgkmcnt(0)" ::: "memory"); \
    __builtin_amdgcn_sched_barrier(0); } while(0)
#define WAITV6() do { asm volatile("s_waitcnt vmcnt(6)" ::: "memory"); \
    __builtin_amdgcn_sched_barrier(0); } while(0)
#define WAITV0() do { asm volatile("s_waitcnt vmcnt(0)" ::: "memory"); \
    __builtin_amdgcn_sched_barrier(0); } while(0)
#define PRIO1() __builtin_amdgcn_s_setprio(1)
#define PRIO0() __builtin_amdgcn_s_setprio(0)

// read 4 A-frags (m-half mh of this wave's 128 rows) x 2 ksteps from buf d
#define RD_A(d, mh) do { \
    _Pragma("unroll") for (int ff = 0; ff < 4; ++ff) { \
      _Pragma("unroll") for (int ks = 0; ks < 2; ++ks) { \
        const int rr = ((mh)*4 + ff)*16 + m15; \
        a[ff*2+ks] = *reinterpret_cast<const bf16x8*>( \
            &sm[(d)*32768 + wm*8192 + rr*64 + ((ks*4 + quad) ^ (m15 & 7))*8]); \
    } } } while(0)

// read 2 B-frags (n-pair np: frags np*2, np*2+1) x 2 ksteps from buf d
#define RD_B(d, np) do { \
    _Pragma("unroll") for (int nn = 0; nn < 2; ++nn) { \
      _Pragma("unroll") for (int ks = 0; ks < 2; ++ks) { \
        const int rr = (wn & 1)*64 + ((np)*2 + nn)*16 + m15; \
        b[((np)*2 + nn)*2 + ks] = *reinterpret_cast<const bf16x8*>( \
            &sm[(d)*32768 + 16384 + (wn >> 1)*8192 + rr*64 + ((ks*4 + quad) ^ (m15 & 7))*8]); \
    } } } while(0)

// 16 MFMAs, ks-outer: 8 independent, then the 8 dependent partners
#define MQk(F0, NF0) do { \
    _Pragma("unroll") for (int ks = 0; ks < 2; ++ks) { \
      _Pragma("unroll") for (int ff = 0; ff < 4; ++ff) { \
        _Pragma("unroll") for (int nn = 0; nn < 2; ++nn) { \
          acc[(F0)+ff][(NF0)+nn] = \
            mfma32(a[ff*2+ks], b[((NF0)+nn)*2+ks], acc[(F0)+ff][(NF0)+nn]); \
    } } } } while(0)

// phases of K-tile s (buffer d = s&1, compile-time via 2x unroll)
#define PH1(d) do { RD_A(d,0); RD_B(d,0); STG(s+1, 3); \
    BARX(); WAITL(); PRIO1(); MQk(0,0); PRIO0(); BARX(); } while(0)
#define PH2(d) do { RD_B(d,1); \
    BARX(); WAITL(); PRIO1(); MQk(0,2); PRIO0(); BARX(); } while(0)
#define PH3(d) do { RD_A(d,1); STG(s+2, 0); \
    BARX(); WAITL(); PRIO1(); MQk(4,2); PRIO0(); BARX(); } while(0)
#define PH4(d) do { STG(s+2, 1); STG(s+2, 2); \
    BARX(); PRIO1(); MQk(4,0); PRIO0(); WAITV6(); BARX(); ++s; } while(0)

// RESID: 0 none, 1 f32 resid[row*N+col], 2 f32 x-skip-cls resid[(row+row/3136+1)*768+col]
template<int KSZ, int NTN, int RESID, bool BIAS, bool GELU_ACT, bool OUTF, bool MASKM>
__global__ __launch_bounds__(512, 2) void gemm_p(
    const u16* __restrict__ A, const u16* __restrict__ Bt,
    const float* __restrict__ bias, const float* __restrict__ resid,
    float* __restrict__ Cf, u16* __restrict__ Cb,
    int N, int lda, int ldb, int Mvalid, int ntiles)
{
    constexpr int KT = KSZ >> 6;          // K-tiles (64 each) per output tile
    static_assert((KT & 1) == 0, "KT must be even");
    extern __shared__ u16 sm[];
    const int tid  = threadIdx.x;
    const int w    = tid >> 6;
    const int l    = tid & 63;
    const int m15  = l & 15;
    const int quad = l >> 4;
    const int wm   = w >> 2;     // 0..1  (M half: 128 rows)
    const int wn   = w & 3;      // 0..3  (N quarter: 64 cols)

    // contiguous tile range for this block
    const int nb   = (int)gridDim.x;
    const int bid  = (int)blockIdx.x;
    const int base = ntiles / nb;
    const int rem  = ntiles - base * nb;
    const int t0   = bid * base + (bid < rem ? bid : rem);
    const int len  = base + (bid < rem ? 1 : 0);
    if (len <= 0) return;
    const int s_hi = len * KT;

    // staging geometry: lane covers row (w*8 + l/8) (+64 per 2nd issue,
    // +128 per half), logical 16B-chunk (l&7)^(l>>3)  [inverse swizzle]
    const int srow   = w*8 + (l >> 3);
    const int schunk = ((l & 7) ^ (l >> 3)) * 8;
    const int w512   = w * 512;

    auto STG = [&](int sp, int h4) {      // h4: 0=B.h0 1=B.h1 2=A.h0 3=A.h1
        const int dd = (sp & 1) * 32768;  // LDS dest from TRUE parity
        const int sg = sp < s_hi ? sp : s_hi - 1;   // clamp source (tail dummy)
        const int tau = sg / KT;                    // compile-time divisor
        const int kk  = sg - tau * KT;
        const int tt  = t0 + tau;
        const int mt  = tt / NTN;                   // compile-time divisor
        const int nt  = tt - mt * NTN;
        const int k0  = kk << 6;
        const int h   = h4 & 1;
        if (h4 & 2) {
            const u16* g = A + (size_t)(mt*256 + h*128 + srow) * lda + k0 + schunk;
            u16* lp = sm + dd + h*8192 + w512;
            async_ld16(g, lp);
            async_ld16(g + (size_t)64 * lda, lp + 4096);
        } else {
            const u16* g = Bt + (size_t)(nt*256 + h*128 + srow) * ldb + k0 + schunk;
            u16* lp = sm + dd + 16384 + h*8192 + w512;
            async_ld16(g, lp);
            async_ld16(g + (size_t)64 * ldb, lp + 4096);
        }
    };

    bf16x8 a[8], b[8];
    floatx4 acc[8][4];
    #pragma unroll
    for (int f = 0; f < 8; ++f)
        #pragma unroll
        for (int nf = 0; nf < 4; ++nf) acc[f][nf] = fzero();

    // prologue: tile0 fully (8 loads, oldest), then tile1 {B0,B1,A0} (6 loads);
    // vmcnt(6) -> tile0 complete, 6 outstanding. tile1.A1 arrives at PH1(0).
    STG(0, 2); STG(0, 0); STG(0, 1); STG(0, 3);
    STG(1, 0); STG(1, 1); STG(1, 2);
    WAITV6(); BARX();

    int s = 0;
    for (int tl = 0; tl < len; ++tl) {
        #pragma unroll 1
        for (int k2 = 0; k2 < KT; k2 += 2) {    // s even at loop top
            PH1(0); PH2(0); PH3(0); PH4(0);
            PH1(1); PH2(1); PH3(1); PH4(1);
        }
        // ---------------- epilogue (register -> global, no LDS) ----------------
        {
            const int tt = t0 + tl;
            const int mt = tt / NTN;
            const int nt = tt - mt * NTN;
            const long m0 = (long)mt * 256;
            const long n0 = (long)nt * 256;
            float bv[4];
            #pragma unroll
            for (int nf = 0; nf < 4; ++nf)
                bv[nf] = BIAS ? bias[n0 + wn*64 + nf*16 + m15] : 0.f;
            #pragma unroll
            for (int f = 0; f < 8; ++f) {
                #pragma unroll
                for (int nf = 0; nf < 4; ++nf) {
                    const long col = n0 + wn*64 + nf*16 + m15;
                    #pragma unroll
                    for (int r = 0; r < 4; ++r) {
                        const long row = m0 + wm*128 + f*16 + quad*4 + r;
                        if constexpr (MASKM) { if (row >= Mvalid) continue; }
                        float v = acc[f][nf][r] + bv[nf];
                        if constexpr (RESID == 1) v += resid[(size_t)row * N + col];
                        if constexpr (RESID == 2) v += resid[(size_t)(row + row/3136 + 1) * 768 + col];
                        if constexpr (GELU_ACT)   v = 0.5f * v * (1.f + erff(v * 0.70710678118f));
                        if constexpr (OUTF) Cf[(size_t)row * N + col] = v;
                        else                Cb[(size_t)row * N + col] = f2bf(v);
                    }
                }
            }
            #pragma unroll
            for (int f = 0; f < 8; ++f)
                #pragma unroll
                for (int nf = 0; nf < 4; ++nf) acc[f][nf] = fzero();
        }
    }
    WAITV0();   // drain DMA before LDS is reallocated to another block
}

// ---------- fused attention (flash-style), one wave per (seq, head, q-tile) ----------
template<int S, int NQ, int NIT>
__global__ __launch_bounds__(256) void attn_kernel(
    const u16* __restrict__ qkv, u16* __restrict__ out, int ntask)
{
    __shared__ __attribute__((aligned(16))) u16 P_lds[4][16*32];
    const int wave = threadIdx.x >> 6;
    const int lane = threadIdx.x & 63;
    const int task = blockIdx.x * 4 + wave;
    if (task >= ntask) return;
    const int seq  = task / (12 * NQ);
    const int rem  = task - seq * (12 * NQ);
    const int head = rem / NQ;
    const int qt   = rem - head * NQ;
    const int m15  = lane & 15;
    const int quad = lane >> 4;
    const size_t base = (size_t)seq * S;

    const u16* qp = qkv + (base + qt*16 + m15) * 2304 + head*64 + quad*8;
    const bf16x8 Qf0 = *reinterpret_cast<const bf16x8*>(qp);
    const bf16x8 Qf1 = *reinterpret_cast<const bf16x8*>(qp + 32);

    floatx4 Oacc[4];
    #pragma unroll
    for (int c = 0; c < 4; ++c) Oacc[c] = fzero();
    float mrun = -__builtin_inff();
    float lrun = 0.f;
    u16* P = &P_lds[wave][0];

    for (int it = 0; it < NIT; ++it) {
        const int j0 = it * 32;
        floatx4 st[2];
        #pragma unroll
        for (int h2 = 0; h2 < 2; ++h2) {
            const u16* kp = qkv + (base + j0 + h2*16 + m15) * 2304 + 768 + head*64 + quad*8;
            const bf16x8 K0 = *reinterpret_cast<const bf16x8*>(kp);
            const bf16x8 K1 = *reinterpret_cast<const bf16x8*>(kp + 32);
            floatx4 z = fzero();
            z = mfma32(K0, Qf0, z);
            st[h2] = mfma32(K1, Qf1, z);
        }
        float sc[8];
        #pragma unroll
        for (int h2 = 0; h2 < 2; ++h2)
            #pragma unroll
            for (int r = 0; r < 4; ++r) {
                const int jj = j0 + h2*16 + quad*4 + r;
                sc[h2*4+r] = (jj < S) ? st[h2][r] * 0.125f : -__builtin_inff();
            }
        float tmax = sc[0];
        #pragma unroll
        for (int k = 1; k < 8; ++k) tmax = fmaxf(tmax, sc[k]);
        tmax = fmaxf(tmax, __shfl_xor(tmax, 16));
        tmax = fmaxf(tmax, __shfl_xor(tmax, 32));
        const float mnew = fmaxf(mrun, tmax);
        float p[8], tsum = 0.f;
        #pragma unroll
        for (int k = 0; k < 8; ++k) { p[k] = __expf(sc[k] - mnew); tsum += p[k]; }
        tsum += __shfl_xor(tsum, 16);
        tsum += __shfl_xor(tsum, 32);
        const float alpha = __expf(mrun - mnew);
        lrun = lrun * alpha + tsum;
        mrun = mnew;
        #pragma unroll
        for (int r = 0; r < 4; ++r) {             // rescale O rows (row = quad*4+r)
            const float ar = __shfl(alpha, quad*4 + r);
            #pragma unroll
            for (int c = 0; c < 4; ++c) Oacc[c][r] *= ar;
        }
        // P round-trip through LDS: C-layout -> A-operand layout
        #pragma unroll
        for (int h2 = 0; h2 < 2; ++h2)
            #pragma unroll
            for (int r = 0; r < 4; ++r)
                P[m15*32 + h2*16 + quad*4 + r] = f2bf(p[h2*4+r]);
        const bf16x8 Pf = *reinterpret_cast<const bf16x8*>(&P[m15*32 + quad*8]);
        #pragma unroll
        for (int c = 0; c < 4; ++c) {             // V in B-operand layout (scattered u16)
            union { u16 u[8]; bf16x8 v; } vf;
            #pragma unroll
            for (int jj2 = 0; jj2 < 8; ++jj2)
                vf.u[jj2] = qkv[(base + j0 + quad*8 + jj2) * 2304 + 1536 + head*64 + c*16 + m15];
            Oacc[c] = mfma32(Pf, vf.v, Oacc[c]);
        }
    }
    const float linv_self = 1.f / lrun;
    #pragma unroll
    for (int r = 0; r < 4; ++r) {
        const int prow = qt*16 + quad*4 + r;
        const float linv = __shfl(linv_self, quad*4 + r);
        if (prow < S) {
            u16* op = out + (base + prow) * 768 + head*64 + m15;
            #pragma unroll
            for (int c = 0; c < 4; ++c) op[c*16] = f2bf(Oacc[c][r] * linv);
        }
    }
}

// ---------- host ----------
extern "C" void kernel_launch(void* const* d_in, const int* in_sizes, int n_in,
                              void* d_out, int out_size, void* d_ws, size_t ws_size,
                              hipStream_t stream)
{
    (void)in_sizes; (void)n_in; (void)out_size; (void)ws_size;
    const float* x        = (const float*)d_in[0];
    const float* tn1_w    = (const float*)d_in[1];
    const float* tn1_b    = (const float*)d_in[2];
    const float* t_qkv_w  = (const float*)d_in[3];
    const float* t_proj_w = (const float*)d_in[4];
    const float* t_proj_b = (const float*)d_in[5];
    const float* tfc_w    = (const float*)d_in[6];
    const float* tfc_b    = (const float*)d_in[7];
    const float* n1_w     = (const float*)d_in[8];
    const float* n1_b     = (const float*)d_in[9];
    const float* s_qkv_w  = (const float*)d_in[10];
    const float* s_proj_w = (const float*)d_in[11];
    const float* s_proj_b = (const float*)d_in[12];
    const float* n2_w     = (const float*)d_in[13];
    const float* n2_b     = (const float*)d_in[14];
    const float* fc1_w    = (const float*)d_in[15];
    const float* fc1_b    = (const float*)d_in[16];
    const float* fc2_w    = (const float*)d_in[17];
    const float* fc2_b    = (const float*)d_in[18];
    float* out = (float*)d_out;

    char* ws = (char*)d_ws;
    size_t off = 0;
    auto alloc = [&](size_t bytes) -> void* {
        void* p = ws + off;
        off += (bytes + 255) & ~(size_t)255;
        return p;
    };
    // weights (bf16, transposed to [N][K])           total ~20.1 MB
    u16* wt_tqkv  = (u16*)alloc((size_t)768*2304*2);
    u16* wt_tproj = (u16*)alloc((size_t)768*768*2);
    u16* wt_tfc   = (u16*)alloc((size_t)768*768*2);
    u16* wt_sqkv  = (u16*)alloc((size_t)768*2304*2);
    u16* wt_sproj = (u16*)alloc((size_t)768*768*2);
    u16* wt_fc1   = (u16*)alloc((size_t)768*3072*2);
    u16* wt_fc2   = (u16*)alloc((size_t)3072*768*2);
    // activation slots (aliased lifetimes). Slots read as GEMM-A with a
    // 99th 256-row M-tile need 25344 rows allocated (tail rows = garbage,
    // masked on store).
    u16* slotA = (u16*)alloc((size_t)25280*2304*2);  // qkv_t / qkv_s / h1 (116.5 MB)
    u16* slotB = (u16*)alloc((size_t)25216*768*2);   // xt2 bf16 (38.7 MB)
    u16* slotD = (u16*)alloc((size_t)25344*768*2);   // ln_t/attn_t/ln_s/attn_s/ln2 (38.9 MB)
    u16* slotE = (u16*)alloc((size_t)25216*768*2);   // hp / rs bf16 (38.7 MB)

    dim3 tb(32, 8);
    transpose_w<<<dim3(72, 24), tb, 0, stream>>>(t_qkv_w,  wt_tqkv,  768, 2304);
    transpose_w<<<dim3(24, 24), tb, 0, stream>>>(t_proj_w, wt_tproj, 768, 768);
    transpose_w<<<dim3(24, 24), tb, 0, stream>>>(tfc_w,    wt_tfc,   768, 768);
    transpose_w<<<dim3(72, 24), tb, 0, stream>>>(s_qkv_w,  wt_sqkv,  768, 2304);
    transpose_w<<<dim3(24, 24), tb, 0, stream>>>(s_proj_w, wt_sproj, 768, 768);
    transpose_w<<<dim3(96, 24), tb, 0, stream>>>(fc1_w,    wt_fc1,   768, 3072);
    transpose_w<<<dim3(24, 96), tb, 0, stream>>>(fc2_w,    wt_fc2,   3072, 768);

    const size_t GLDS = 131072;   // 128 KiB dynamic LDS for gemm_p
    const int    GP   = 256;      // persistent grid

    u16* lnT  = slotD;
    u16* qkvT = slotA;
    ln_kernel<0><<<25088/4, 256, 0, stream>>>(x, nullptr, tn1_w, tn1_b, lnT, 25088);
    gemm_p<768,9,0,false,false,false,false><<<GP, 512, GLDS, stream>>>(
        lnT, wt_tqkv, nullptr, nullptr, nullptr, qkvT, 2304, 768, 768, 0, 98*9);

    u16* attnT = slotD;
    attn_kernel<16,1,1><<<18816/4, 256, 0, stream>>>(qkvT, attnT, 18816);

    u16* hp = slotE;
    gemm_p<768,3,0,true,false,false,false><<<GP, 512, GLDS, stream>>>(
        attnT, wt_tproj, t_proj_b, nullptr, nullptr, hp, 768, 768, 768, 0, 98*3);

    u16* xt2 = slotB;   // tfc + bias + x-residual (skip-cls map) -> bf16
    gemm_p<768,3,2,true,false,false,false><<<GP, 512, GLDS, stream>>>(
        hp, wt_tfc, tfc_b, x, nullptr, xt2, 768, 768, 768, 0, 98*3);

    u16* lnS = slotD;
    ln_kernel<1><<<25216/4, 256, 0, stream>>>(x, xt2, n1_w, n1_b, lnS, 25216);

    u16* qkvS = slotA;
    gemm_p<768,9,0,false,false,false,true><<<GP, 512, GLDS, stream>>>(
        lnS, wt_sqkv, nullptr, nullptr, nullptr, qkvS, 2304, 768, 768, 25216, 99*9);

    u16* attnS = slotD;
    attn_kernel<197,13,7><<<19968/4, 256, 0, stream>>>(qkvS, attnS, 19968);

    u16* rsb = slotE;
    gemm_p<768,3,0,true,false,false,true><<<GP, 512, GLDS, stream>>>(
        attnS, wt_sproj, s_proj_b, nullptr, nullptr, rsb, 768, 768, 768, 25216, 99*3);

    float* xnew = out;                // x_new lives in d_out
    u16* ln2 = slotD;
    combine_ln2<<<25096/4, 256, 0, stream>>>(x, xt2, rsb, n2_w, n2_b, xnew, ln2, 25096);

    // MLP split into two hidden halves (h1 fits in slotA)
    u16* h1 = slotA;
    for (int half = 0; half < 2; ++half) {
        const u16* w1h = wt_fc1 + (size_t)half * 1536 * 768;   // rows [N-half][768]
        const float* b1h = fc1_b + half * 1536;
        gemm_p<768,6,0,true,true,false,true><<<GP, 512, GLDS, stream>>>(
            ln2, w1h, b1h, nullptr, nullptr, h1, 1536, 768, 768, 25096, 99*6);
        const u16* w2h = wt_fc2 + (size_t)half * 1536;         // [768][3072] K-offset
        if (half == 0)
            gemm_p<1536,3,1,true,false,true,true><<<GP, 512, GLDS, stream>>>(
                h1, w2h, fc2_b, out, out, nullptr, 768, 1536, 3072, 25096, 99*3);
        else
            gemm_p<1536,3,1,false,false,true,true><<<GP, 512, GLDS, stream>>>(
                h1, w2h, nullptr, out, out, nullptr, 768, 1536, 3072, 25096, 99*3);
    }
}

// Round 5
// 1467.344 us; speedup vs baseline: 1.0141x; 1.0141x over previous
//
#include <hip/hip_runtime.h>
#include <cstdint>

using u16 = unsigned short;
using u32 = unsigned int;

typedef __bf16 bf16x8 __attribute__((ext_vector_type(8)));
typedef float  floatx4 __attribute__((ext_vector_type(4)));

#define DEV static __device__ __forceinline__

// ---------- helpers ----------
DEV u16 f2bf(float f) {                 // f32 -> bf16 RNE
    u32 u = __float_as_uint(f);
    u += 0x7FFFu + ((u >> 16) & 1u);
    return (u16)(u >> 16);
}
DEV float bf2f(u16 v) { return __uint_as_float(((u32)v) << 16); }

DEV floatx4 mfma32(bf16x8 a, bf16x8 b, floatx4 c) {
    return __builtin_amdgcn_mfma_f32_16x16x32_bf16(a, b, c, 0, 0, 0);
}

DEV floatx4 fzero() { floatx4 z; z[0]=0.f; z[1]=0.f; z[2]=0.f; z[3]=0.f; return z; }

typedef __attribute__((address_space(3))) u32 as3_u32;
typedef __attribute__((address_space(1))) u32 as1_u32;

// async global->LDS, 16B per lane; LDS dest = wave-uniform base + lane*16.
DEV void async_ld16(const u16* g, u16* l) {
    __builtin_amdgcn_global_load_lds(
        (const as1_u32*)g, (as3_u32*)l, 16, 0, 0);
}

// ---------- weight transpose: W[K][N] f32 -> Wt[N][K] bf16 ----------
__global__ __launch_bounds__(256) void transpose_w(
    const float* __restrict__ W, u16* __restrict__ Wt, int K, int N)
{
    __shared__ float t[32][33];
    const int tx = threadIdx.x, ty = threadIdx.y;   // block 32x8
    const int gx = blockIdx.x * 32;                 // N dim
    const int gy = blockIdx.y * 32;                 // K dim
    #pragma unroll
    for (int i = 0; i < 4; ++i)
        t[ty + i*8][tx] = W[(size_t)(gy + ty + i*8) * N + gx + tx];
    __syncthreads();
    #pragma unroll
    for (int i = 0; i < 4; ++i)
        Wt[(size_t)(gx + ty + i*8) * K + gy + tx] = f2bf(t[tx][ty + i*8]);
}

// ---------- LayerNorm (wave per row, 4 rows/block), writes bf16 ----------
template<int MODE>
__global__ __launch_bounds__(256) void ln_kernel(
    const float* __restrict__ xp, const u16* __restrict__ xt2,
    const float* __restrict__ w, const float* __restrict__ b,
    u16* __restrict__ out, int nrows)
{
    const int row = blockIdx.x * 4 + (threadIdx.x >> 6);
    if (row >= nrows) return;
    const int lane = threadIdx.x & 63;
    float vals[12];
    if constexpr (MODE == 0) {
        const float* src = xp + (size_t)(row + row/3136 + 1) * 768;
        #pragma unroll
        for (int j = 0; j < 3; ++j) {
            float4 v = reinterpret_cast<const float4*>(src)[j*64 + lane];
            vals[j*4+0]=v.x; vals[j*4+1]=v.y; vals[j*4+2]=v.z; vals[j*4+3]=v.w;
        }
    } else {
        const int bt = row / 197;
        const int p  = row - bt * 197;
        const int b0 = bt >> 4, tt = bt & 15;
        if (p == 0) {
            const float* src = xp + (size_t)b0 * 3137 * 768;
            #pragma unroll
            for (int j = 0; j < 3; ++j) {
                float4 v = reinterpret_cast<const float4*>(src)[j*64 + lane];
                vals[j*4+0]=v.x; vals[j*4+1]=v.y; vals[j*4+2]=v.z; vals[j*4+3]=v.w;
            }
        } else {
            const u16* src = xt2 + (size_t)(b0*3136 + (p-1)*16 + tt) * 768;
            #pragma unroll
            for (int j = 0; j < 3; ++j) {
                uint2 q = reinterpret_cast<const uint2*>(src)[j*64 + lane];
                vals[j*4+0] = bf2f((u16)(q.x & 0xFFFF));
                vals[j*4+1] = bf2f((u16)(q.x >> 16));
                vals[j*4+2] = bf2f((u16)(q.y & 0xFFFF));
                vals[j*4+3] = bf2f((u16)(q.y >> 16));
            }
        }
    }
    float s = 0.f, ss = 0.f;
    #pragma unroll
    for (int e = 0; e < 12; ++e) { s += vals[e]; ss += vals[e]*vals[e]; }
    #pragma unroll
    for (int o = 32; o > 0; o >>= 1) { s += __shfl_xor(s, o); ss += __shfl_xor(ss, o); }
    const float mean = s * (1.f/768.f);
    const float var  = ss * (1.f/768.f) - mean*mean;
    const float rstd = rsqrtf(var + 1e-5f);
    #pragma unroll
    for (int j = 0; j < 3; ++j) {
        const int c4 = (j*64 + lane) * 4;
        union { u16 u[4]; uint2 q; } o;
        #pragma unroll
        for (int e = 0; e < 4; ++e)
            o.u[e] = f2bf((vals[j*4+e] - mean)*rstd*w[c4+e] + b[c4+e]);
        *reinterpret_cast<uint2*>(&out[(size_t)row*768 + c4]) = o.q;
    }
}

// ---------- combine: x_new = concat residuals (f32 -> d_out), then LN(n2) bf16 ----------
__global__ __launch_bounds__(256) void combine_ln2(
    const float* __restrict__ xp, const u16* __restrict__ xt2,
    const u16* __restrict__ rsb, const float* __restrict__ w, const float* __restrict__ b,
    float* __restrict__ xnew, u16* __restrict__ ln2, int nrows)
{
    const int row = blockIdx.x * 4 + (threadIdx.x >> 6);
    if (row >= nrows) return;
    const int lane = threadIdx.x & 63;
    const int b0 = row / 3137;
    const int j  = row - b0 * 3137;
    float vals[12];
    if (j == 0) {       // cls row: x[b,0] + mean_t rs[(b,t) seq, token 0]
        #pragma unroll
        for (int e = 0; e < 12; ++e) {
            const int c = e*64 + lane;
            float acc = 0.f;
            for (int t = 0; t < 16; ++t)
                acc += bf2f(rsb[(size_t)(b0*16 + t) * 197 * 768 + c]);
            vals[e] = xp[(size_t)row*768 + c] + acc * (1.f/16.f);
        }
    } else {
        const int n_idx = j - 1;
        const int hw = n_idx >> 4, tt = n_idx & 15;
        const u16* a  = xt2 + (size_t)(b0*3136 + n_idx) * 768;
        const u16* r2 = rsb + (size_t)((b0*16 + tt)*197 + 1 + hw) * 768;
        #pragma unroll
        for (int e = 0; e < 12; ++e) {
            const int c = e*64 + lane;
            vals[e] = bf2f(a[c]) + bf2f(r2[c]);
        }
    }
    float s = 0.f, ss = 0.f;
    #pragma unroll
    for (int e = 0; e < 12; ++e) { s += vals[e]; ss += vals[e]*vals[e]; }
    #pragma unroll
    for (int o = 32; o > 0; o >>= 1) { s += __shfl_xor(s, o); ss += __shfl_xor(ss, o); }
    const float mean = s * (1.f/768.f);
    const float var  = ss * (1.f/768.f) - mean*mean;
    const float rstd = rsqrtf(var + 1e-5f);
    #pragma unroll
    for (int e = 0; e < 12; ++e) {
        const int c = e*64 + lane;
        xnew[(size_t)row*768 + c] = vals[e];
        ln2[(size_t)row*768 + c]  = f2bf((vals[e] - mean)*rstd*w[c] + b[c]);
    }
}

// ============================================================================
// PERSISTENT GEMM, 256x256 tiles, BK=64, 8 waves (2Mx4N).
// Same pipeline as round 3 (liveness-proven rotation, vmcnt(6)/K-tile).
// OUTB epilogue packs 4 consecutive bf16 cols into a uint2 per lane via
// two intra-quad __shfl_xor levels (lanes ^1, ^2) -> 8B/lane stores, 32B-dense
// row segments, 32 store instrs/wave/tile (was 128 scattered u16). No LDS, no
// barrier, overlaps in-flight prefetch; decouples store drain from vmcnt gates
// (8x fewer outstanding store ops at gate time).
// ============================================================================

#define BARX() do { __builtin_amdgcn_sched_barrier(0); asm volatile("" ::: "memory"); \
    __builtin_amdgcn_s_barrier(); asm volatile("" ::: "memory"); \
    __builtin_amdgcn_sched_barrier(0); } while(0)
#define WAITL() do { asm volatile("s_waitcnt lgkmcnt(0)" ::: "memory"); \
    __builtin_amdgcn_sched_barrier(0); } while(0)
#define WAITV6() do { asm volatile("s_waitcnt vmcnt(6)" ::: "memory"); \
    __builtin_amdgcn_sched_barrier(0); } while(0)
#define WAITV0() do { asm volatile("s_waitcnt vmcnt(0)" ::: "memory"); \
    __builtin_amdgcn_sched_barrier(0); } while(0)
#define PRIO1() __builtin_amdgcn_s_setprio(1)
#define PRIO0() __builtin_amdgcn_s_setprio(0)

// read 4 A-frags (m-half mh of this wave's 128 rows) x 2 ksteps from buf d
#define RD_A(d, mh) do { \
    _Pragma("unroll") for (int ff = 0; ff < 4; ++ff) { \
      _Pragma("unroll") for (int ks = 0; ks < 2; ++ks) { \
        const int rr = ((mh)*4 + ff)*16 + m15; \
        a[ff*2+ks] = *reinterpret_cast<const bf16x8*>( \
            &sm[(d)*32768 + wm*8192 + rr*64 + ((ks*4 + quad) ^ (m15 & 7))*8]); \
    } } } while(0)

// read 2 B-frags (n-pair np: frags np*2, np*2+1) x 2 ksteps from buf d
#define RD_B(d, np) do { \
    _Pragma("unroll") for (int nn = 0; nn < 2; ++nn) { \
      _Pragma("unroll") for (int ks = 0; ks < 2; ++ks) { \
        const int rr = (wn & 1)*64 + ((np)*2 + nn)*16 + m15; \
        b[((np)*2 + nn)*2 + ks] = *reinterpret_cast<const bf16x8*>( \
            &sm[(d)*32768 + 16384 + (wn >> 1)*8192 + rr*64 + ((ks*4 + quad) ^ (m15 & 7))*8]); \
    } } } while(0)

// 16 MFMAs, ks-outer: 8 independent, then the 8 dependent partners
#define MQk(F0, NF0) do { \
    _Pragma("unroll") for (int ks = 0; ks < 2; ++ks) { \
      _Pragma("unroll") for (int ff = 0; ff < 4; ++ff) { \
        _Pragma("unroll") for (int nn = 0; nn < 2; ++nn) { \
          acc[(F0)+ff][(NF0)+nn] = \
            mfma32(a[ff*2+ks], b[((NF0)+nn)*2+ks], acc[(F0)+ff][(NF0)+nn]); \
    } } } } while(0)

// phases of K-tile s (buffer d = s&1, compile-time via 2x unroll)
#define PH1(d) do { RD_A(d,0); RD_B(d,0); STG(s+1, 3); \
    BARX(); WAITL(); PRIO1(); MQk(0,0); PRIO0(); BARX(); } while(0)
#define PH2(d) do { RD_B(d,1); \
    BARX(); WAITL(); PRIO1(); MQk(0,2); PRIO0(); BARX(); } while(0)
#define PH3(d) do { RD_A(d,1); STG(s+2, 0); \
    BARX(); WAITL(); PRIO1(); MQk(4,2); PRIO0(); BARX(); } while(0)
#define PH4(d) do { STG(s+2, 1); STG(s+2, 2); \
    BARX(); PRIO1(); MQk(4,0); PRIO0(); WAITV6(); BARX(); ++s; } while(0)

// RESID: 0 none, 1 f32 resid[row*N+col], 2 f32 x-skip-cls resid[(row+row/3136+1)*768+col]
template<int KSZ, int NTN, int RESID, bool BIAS, bool GELU_ACT, bool OUTF, bool MASKM>
__global__ __launch_bounds__(512, 2) void gemm_p(
    const u16* __restrict__ A, const u16* __restrict__ Bt,
    const float* __restrict__ bias, const float* __restrict__ resid,
    float* __restrict__ Cf, u16* __restrict__ Cb,
    int N, int lda, int ldb, int Mvalid, int ntiles)
{
    constexpr int KT = KSZ >> 6;          // K-tiles (64 each) per output tile
    static_assert((KT & 1) == 0, "KT must be even");
    extern __shared__ u16 sm[];
    const int tid  = threadIdx.x;
    const int w    = tid >> 6;
    const int l    = tid & 63;
    const int m15  = l & 15;
    const int quad = l >> 4;
    const int wm   = w >> 2;     // 0..1  (M half: 128 rows)
    const int wn   = w & 3;      // 0..3  (N quarter: 64 cols)

    // contiguous tile range for this block
    const int nb   = (int)gridDim.x;
    const int bid  = (int)blockIdx.x;
    const int base = ntiles / nb;
    const int rem  = ntiles - base * nb;
    const int t0   = bid * base + (bid < rem ? bid : rem);
    const int len  = base + (bid < rem ? 1 : 0);
    if (len <= 0) return;
    const int s_hi = len * KT;

    // staging geometry: lane covers row (w*8 + l/8) (+64 per 2nd issue,
    // +128 per half), logical 16B-chunk (l&7)^(l>>3)  [inverse swizzle]
    const int srow   = w*8 + (l >> 3);
    const int schunk = ((l & 7) ^ (l >> 3)) * 8;
    const int w512   = w * 512;

    auto STG = [&](int sp, int h4) {      // h4: 0=B.h0 1=B.h1 2=A.h0 3=A.h1
        const int dd = (sp & 1) * 32768;  // LDS dest from TRUE parity
        const int sg = sp < s_hi ? sp : s_hi - 1;   // clamp source (tail dummy)
        const int tau = sg / KT;                    // compile-time divisor
        const int kk  = sg - tau * KT;
        const int tt  = t0 + tau;
        const int mt  = tt / NTN;                   // compile-time divisor
        const int nt  = tt - mt * NTN;
        const int k0  = kk << 6;
        const int h   = h4 & 1;
        if (h4 & 2) {
            const u16* g = A + (size_t)(mt*256 + h*128 + srow) * lda + k0 + schunk;
            u16* lp = sm + dd + h*8192 + w512;
            async_ld16(g, lp);
            async_ld16(g + (size_t)64 * lda, lp + 4096);
        } else {
            const u16* g = Bt + (size_t)(nt*256 + h*128 + srow) * ldb + k0 + schunk;
            u16* lp = sm + dd + 16384 + h*8192 + w512;
            async_ld16(g, lp);
            async_ld16(g + (size_t)64 * ldb, lp + 4096);
        }
    };

    bf16x8 a[8], b[8];
    floatx4 acc[8][4];
    #pragma unroll
    for (int f = 0; f < 8; ++f)
        #pragma unroll
        for (int nf = 0; nf < 4; ++nf) acc[f][nf] = fzero();

    // prologue: tile0 fully (8 loads, oldest), then tile1 {B0,B1,A0} (6 loads);
    // vmcnt(6) -> tile0 complete, 6 outstanding. tile1.A1 arrives at PH1(0).
    STG(0, 2); STG(0, 0); STG(0, 1); STG(0, 3);
    STG(1, 0); STG(1, 1); STG(1, 2);
    WAITV6(); BARX();

    int s = 0;
    for (int tl = 0; tl < len; ++tl) {
        #pragma unroll 1
        for (int k2 = 0; k2 < KT; k2 += 2) {    // s even at loop top
            PH1(0); PH2(0); PH3(0); PH4(0);
            PH1(1); PH2(1); PH3(1); PH4(1);
        }
        // ---------------- epilogue (register -> global, no LDS) ----------------
        {
            const int tt = t0 + tl;
            const int mt = tt / NTN;
            const int nt = tt - mt * NTN;
            const long m0 = (long)mt * 256;
            const long n0 = (long)nt * 256;
            float bv[4];
            #pragma unroll
            for (int nf = 0; nf < 4; ++nf)
                bv[nf] = BIAS ? bias[n0 + wn*64 + nf*16 + m15] : 0.f;
            if constexpr (!OUTF) {
                // packed bf16 epilogue: 2 intra-quad shfl_xor levels -> uint2/lane
                const int rsel = m15 & 3;
                const int csel = m15 & ~3;
                #pragma unroll
                for (int f = 0; f < 8; ++f) {
                    #pragma unroll
                    for (int nf = 0; nf < 4; ++nf) {
                        float vv[4];
                        #pragma unroll
                        for (int r = 0; r < 4; ++r) {
                            const long row = m0 + wm*128 + f*16 + quad*4 + r;
                            float v = acc[f][nf][r] + bv[nf];
                            if constexpr (RESID == 1)
                                v += resid[(size_t)row * N + (n0 + wn*64 + nf*16 + m15)];
                            if constexpr (RESID == 2)
                                v += resid[(size_t)(row + row/3136 + 1) * 768 + (n0 + wn*64 + nf*16 + m15)];
                            if constexpr (GELU_ACT)
                                v = 0.5f * v * (1.f + erff(v * 0.70710678118f));
                            vv[r] = v;
                        }
                        u32 lo[4], hi[4];
                        #pragma unroll
                        for (int r = 0; r < 4; ++r) {
                            u32 x = (u32)f2bf(vv[r]);
                            u32 y = (u32)__shfl_xor((int)x, 1);
                            u32 p = (m15 & 1) ? (y | (x << 16)) : (x | (y << 16));
                            u32 z = (u32)__shfl_xor((int)p, 2);
                            lo[r] = (m15 & 2) ? z : p;
                            hi[r] = (m15 & 2) ? p : z;
                        }
                        const u32 slo = rsel==0?lo[0]:rsel==1?lo[1]:rsel==2?lo[2]:lo[3];
                        const u32 shi = rsel==0?hi[0]:rsel==1?hi[1]:rsel==2?hi[2]:hi[3];
                        const long row = m0 + wm*128 + f*16 + quad*4 + rsel;
                        const long col = n0 + wn*64 + nf*16 + csel;
                        bool ok = true;
                        if constexpr (MASKM) ok = (row < Mvalid);
                        if (ok) {
                            uint2 qv; qv.x = slo; qv.y = shi;
                            *reinterpret_cast<uint2*>(&Cb[(size_t)row * N + col]) = qv;
                        }
                    }
                }
            } else {
                #pragma unroll
                for (int f = 0; f < 8; ++f) {
                    #pragma unroll
                    for (int nf = 0; nf < 4; ++nf) {
                        const long col = n0 + wn*64 + nf*16 + m15;
                        #pragma unroll
                        for (int r = 0; r < 4; ++r) {
                            const long row = m0 + wm*128 + f*16 + quad*4 + r;
                            if constexpr (MASKM) { if (row >= Mvalid) continue; }
                            float v = acc[f][nf][r] + bv[nf];
                            if constexpr (RESID == 1) v += resid[(size_t)row * N + col];
                            if constexpr (RESID == 2) v += resid[(size_t)(row + row/3136 + 1) * 768 + col];
                            if constexpr (GELU_ACT)   v = 0.5f * v * (1.f + erff(v * 0.70710678118f));
                            Cf[(size_t)row * N + col] = v;
                        }
                    }
                }
            }
            #pragma unroll
            for (int f = 0; f < 8; ++f)
                #pragma unroll
                for (int nf = 0; nf < 4; ++nf) acc[f][nf] = fzero();
        }
    }
    WAITV0();   // drain DMA before LDS is reallocated to another block
}

// ---------- fused attention (flash-style), one wave per (seq, head, q-tile) ----------
template<int S, int NQ, int NIT>
__global__ __launch_bounds__(256) void attn_kernel(
    const u16* __restrict__ qkv, u16* __restrict__ out, int ntask)
{
    __shared__ __attribute__((aligned(16))) u16 P_lds[4][16*32];
    const int wave = threadIdx.x >> 6;
    const int lane = threadIdx.x & 63;
    const int task = blockIdx.x * 4 + wave;
    if (task >= ntask) return;
    const int seq  = task / (12 * NQ);
    const int rem  = task - seq * (12 * NQ);
    const int head = rem / NQ;
    const int qt   = rem - head * NQ;
    const int m15  = lane & 15;
    const int quad = lane >> 4;
    const size_t base = (size_t)seq * S;

    const u16* qp = qkv + (base + qt*16 + m15) * 2304 + head*64 + quad*8;
    const bf16x8 Qf0 = *reinterpret_cast<const bf16x8*>(qp);
    const bf16x8 Qf1 = *reinterpret_cast<const bf16x8*>(qp + 32);

    floatx4 Oacc[4];
    #pragma unroll
    for (int c = 0; c < 4; ++c) Oacc[c] = fzero();
    float mrun = -__builtin_inff();
    float lrun = 0.f;
    u16* P = &P_lds[wave][0];

    for (int it = 0; it < NIT; ++it) {
        const int j0 = it * 32;
        floatx4 st[2];
        #pragma unroll
        for (int h2 = 0; h2 < 2; ++h2) {
            const u16* kp = qkv + (base + j0 + h2*16 + m15) * 2304 + 768 + head*64 + quad*8;
            const bf16x8 K0 = *reinterpret_cast<const bf16x8*>(kp);
            const bf16x8 K1 = *reinterpret_cast<const bf16x8*>(kp + 32);
            floatx4 z = fzero();
            z = mfma32(K0, Qf0, z);
            st[h2] = mfma32(K1, Qf1, z);
        }
        float sc[8];
        #pragma unroll
        for (int h2 = 0; h2 < 2; ++h2)
            #pragma unroll
            for (int r = 0; r < 4; ++r) {
                const int jj = j0 + h2*16 + quad*4 + r;
                sc[h2*4+r] = (jj < S) ? st[h2][r] * 0.125f : -__builtin_inff();
            }
        float tmax = sc[0];
        #pragma unroll
        for (int k = 1; k < 8; ++k) tmax = fmaxf(tmax, sc[k]);
        tmax = fmaxf(tmax, __shfl_xor(tmax, 16));
        tmax = fmaxf(tmax, __shfl_xor(tmax, 32));
        const float mnew = fmaxf(mrun, tmax);
        float p[8], tsum = 0.f;
        #pragma unroll
        for (int k = 0; k < 8; ++k) { p[k] = __expf(sc[k] - mnew); tsum += p[k]; }
        tsum += __shfl_xor(tsum, 16);
        tsum += __shfl_xor(tsum, 32);
        const float alpha = __expf(mrun - mnew);
        lrun = lrun * alpha + tsum;
        mrun = mnew;
        #pragma unroll
        for (int r = 0; r < 4; ++r) {             // rescale O rows (row = quad*4+r)
            const float ar = __shfl(alpha, quad*4 + r);
            #pragma unroll
            for (int c = 0; c < 4; ++c) Oacc[c][r] *= ar;
        }
        // P round-trip through LDS: C-layout -> A-operand layout
        #pragma unroll
        for (int h2 = 0; h2 < 2; ++h2)
            #pragma unroll
            for (int r = 0; r < 4; ++r)
                P[m15*32 + h2*16 + quad*4 + r] = f2bf(p[h2*4+r]);
        const bf16x8 Pf = *reinterpret_cast<const bf16x8*>(&P[m15*32 + quad*8]);
        #pragma unroll
        for (int c = 0; c < 4; ++c) {             // V in B-operand layout (scattered u16)
            union { u16 u[8]; bf16x8 v; } vf;
            #pragma unroll
            for (int jj2 = 0; jj2 < 8; ++jj2)
                vf.u[jj2] = qkv[(base + j0 + quad*8 + jj2) * 2304 + 1536 + head*64 + c*16 + m15];
            Oacc[c] = mfma32(Pf, vf.v, Oacc[c]);
        }
    }
    const float linv_self = 1.f / lrun;
    #pragma unroll
    for (int r = 0; r < 4; ++r) {
        const int prow = qt*16 + quad*4 + r;
        const float linv = __shfl(linv_self, quad*4 + r);
        if (prow < S) {
            u16* op = out + (base + prow) * 768 + head*64 + m15;
            #pragma unroll
            for (int c = 0; c < 4; ++c) op[c*16] = f2bf(Oacc[c][r] * linv);
        }
    }
}

// ---------- host ----------
extern "C" void kernel_launch(void* const* d_in, const int* in_sizes, int n_in,
                              void* d_out, int out_size, void* d_ws, size_t ws_size,
                              hipStream_t stream)
{
    (void)in_sizes; (void)n_in; (void)out_size; (void)ws_size;
    const float* x        = (const float*)d_in[0];
    const float* tn1_w    = (const float*)d_in[1];
    const float* tn1_b    = (const float*)d_in[2];
    const float* t_qkv_w  = (const float*)d_in[3];
    const float* t_proj_w = (const float*)d_in[4];
    const float* t_proj_b = (const float*)d_in[5];
    const float* tfc_w    = (const float*)d_in[6];
    const float* tfc_b    = (const float*)d_in[7];
    const float* n1_w     = (const float*)d_in[8];
    const float* n1_b     = (const float*)d_in[9];
    const float* s_qkv_w  = (const float*)d_in[10];
    const float* s_proj_w = (const float*)d_in[11];
    const float* s_proj_b = (const float*)d_in[12];
    const float* n2_w     = (const float*)d_in[13];
    const float* n2_b     = (const float*)d_in[14];
    const float* fc1_w    = (const float*)d_in[15];
    const float* fc1_b    = (const float*)d_in[16];
    const float* fc2_w    = (const float*)d_in[17];
    const float* fc2_b    = (const float*)d_in[18];
    float* out = (float*)d_out;

    char* ws = (char*)d_ws;
    size_t off = 0;
    auto alloc = [&](size_t bytes) -> void* {
        void* p = ws + off;
        off += (bytes + 255) & ~(size_t)255;
        return p;
    };
    // weights (bf16, transposed to [N][K])           total ~20.1 MB
    u16* wt_tqkv  = (u16*)alloc((size_t)768*2304*2);
    u16* wt_tproj = (u16*)alloc((size_t)768*768*2);
    u16* wt_tfc   = (u16*)alloc((size_t)768*768*2);
    u16* wt_sqkv  = (u16*)alloc((size_t)768*2304*2);
    u16* wt_sproj = (u16*)alloc((size_t)768*768*2);
    u16* wt_fc1   = (u16*)alloc((size_t)768*3072*2);
    u16* wt_fc2   = (u16*)alloc((size_t)3072*768*2);
    // activation slots (aliased lifetimes). Slots read as GEMM-A with a
    // 99th 256-row M-tile need 25344 rows allocated (tail rows = garbage,
    // masked on store).
    u16* slotA = (u16*)alloc((size_t)25280*2304*2);  // qkv_t / qkv_s / h1 (116.5 MB)
    u16* slotB = (u16*)alloc((size_t)25216*768*2);   // xt2 bf16 (38.7 MB)
    u16* slotD = (u16*)alloc((size_t)25344*768*2);   // ln_t/attn_t/ln_s/attn_s/ln2 (38.9 MB)
    u16* slotE = (u16*)alloc((size_t)25216*768*2);   // hp / rs bf16 (38.7 MB)

    dim3 tb(32, 8);
    transpose_w<<<dim3(72, 24), tb, 0, stream>>>(t_qkv_w,  wt_tqkv,  768, 2304);
    transpose_w<<<dim3(24, 24), tb, 0, stream>>>(t_proj_w, wt_tproj, 768, 768);
    transpose_w<<<dim3(24, 24), tb, 0, stream>>>(tfc_w,    wt_tfc,   768, 768);
    transpose_w<<<dim3(72, 24), tb, 0, stream>>>(s_qkv_w,  wt_sqkv,  768, 2304);
    transpose_w<<<dim3(24, 24), tb, 0, stream>>>(s_proj_w, wt_sproj, 768, 768);
    transpose_w<<<dim3(96, 24), tb, 0, stream>>>(fc1_w,    wt_fc1,   768, 3072);
    transpose_w<<<dim3(24, 96), tb, 0, stream>>>(fc2_w,    wt_fc2,   3072, 768);

    const size_t GLDS = 131072;   // 128 KiB dynamic LDS for gemm_p
    const int    GP   = 256;      // persistent grid

    u16* lnT  = slotD;
    u16* qkvT = slotA;
    ln_kernel<0><<<25088/4, 256, 0, stream>>>(x, nullptr, tn1_w, tn1_b, lnT, 25088);
    gemm_p<768,9,0,false,false,false,false><<<GP, 512, GLDS, stream>>>(
        lnT, wt_tqkv, nullptr, nullptr, nullptr, qkvT, 2304, 768, 768, 0, 98*9);

    u16* attnT = slotD;
    attn_kernel<16,1,1><<<18816/4, 256, 0, stream>>>(qkvT, attnT, 18816);

    u16* hp = slotE;
    gemm_p<768,3,0,true,false,false,false><<<GP, 512, GLDS, stream>>>(
        attnT, wt_tproj, t_proj_b, nullptr, nullptr, hp, 768, 768, 768, 0, 98*3);

    u16* xt2 = slotB;   // tfc + bias + x-residual (skip-cls map) -> bf16
    gemm_p<768,3,2,true,false,false,false><<<GP, 512, GLDS, stream>>>(
        hp, wt_tfc, tfc_b, x, nullptr, xt2, 768, 768, 768, 0, 98*3);

    u16* lnS = slotD;
    ln_kernel<1><<<25216/4, 256, 0, stream>>>(x, xt2, n1_w, n1_b, lnS, 25216);

    u16* qkvS = slotA;
    gemm_p<768,9,0,false,false,false,true><<<GP, 512, GLDS, stream>>>(
        lnS, wt_sqkv, nullptr, nullptr, nullptr, qkvS, 2304, 768, 768, 25216, 99*9);

    u16* attnS = slotD;
    attn_kernel<197,13,7><<<19968/4, 256, 0, stream>>>(qkvS, attnS, 19968);

    u16* rsb = slotE;
    gemm_p<768,3,0,true,false,false,true><<<GP, 512, GLDS, stream>>>(
        attnS, wt_sproj, s_proj_b, nullptr, nullptr, rsb, 768, 768, 768, 25216, 99*3);

    float* xnew = out;                // x_new lives in d_out
    u16* ln2 = slotD;
    combine_ln2<<<25096/4, 256, 0, stream>>>(x, xt2, rsb, n2_w, n2_b, xnew, ln2, 25096);

    // MLP split into two hidden halves (h1 fits in slotA)
    u16* h1 = slotA;
    for (int half = 0; half < 2; ++half) {
        const u16* w1h = wt_fc1 + (size_t)half * 1536 * 768;   // rows [N-half][768]
        const float* b1h = fc1_b + half * 1536;
        gemm_p<768,6,0,true,true,false,true><<<GP, 512, GLDS, stream>>>(
            ln2, w1h, b1h, nullptr, nullptr, h1, 1536, 768, 768, 25096, 99*6);
        const u16* w2h = wt_fc2 + (size_t)half * 1536;         // [768][3072] K-offset
        if (half == 0)
            gemm_p<1536,3,1,true,false,true,true><<<GP, 512, GLDS, stream>>>(
                h1, w2h, fc2_b, out, out, nullptr, 768, 1536, 3072, 25096, 99*3);
        else
            gemm_p<1536,3,1,false,false,true,true><<<GP, 512, GLDS, stream>>>(
                h1, w2h, nullptr, out, out, nullptr, 768, 1536, 3072, 25096, 99*3);
    }
}

// Round 6
// 1301.736 us; speedup vs baseline: 1.1431x; 1.1272x over previous
//
#include <hip/hip_runtime.h>
#include <cstdint>

using u16 = unsigned short;
using u32 = unsigned int;

typedef __bf16 bf16x8 __attribute__((ext_vector_type(8)));
typedef float  floatx4 __attribute__((ext_vector_type(4)));

#define DEV static __device__ __forceinline__

// ---------- helpers ----------
DEV u16 f2bf(float f) {                 // f32 -> bf16 RNE
    u32 u = __float_as_uint(f);
    u += 0x7FFFu + ((u >> 16) & 1u);
    return (u16)(u >> 16);
}
DEV float bf2f(u16 v) { return __uint_as_float(((u32)v) << 16); }

DEV floatx4 mfma32(bf16x8 a, bf16x8 b, floatx4 c) {
    return __builtin_amdgcn_mfma_f32_16x16x32_bf16(a, b, c, 0, 0, 0);
}

DEV floatx4 fzero() { floatx4 z; z[0]=0.f; z[1]=0.f; z[2]=0.f; z[3]=0.f; return z; }

typedef __attribute__((address_space(3))) u32 as3_u32;
typedef __attribute__((address_space(1))) u32 as1_u32;

// async global->LDS, 16B per lane; LDS dest = wave-uniform base + lane*16.
DEV void async_ld16(const u16* g, u16* l) {
    __builtin_amdgcn_global_load_lds(
        (const as1_u32*)g, (as3_u32*)l, 16, 0, 0);
}

// ---------- weight transpose: W[K][N] f32 -> Wt[N][K] bf16 ----------
__global__ __launch_bounds__(256) void transpose_w(
    const float* __restrict__ W, u16* __restrict__ Wt, int K, int N)
{
    __shared__ float t[32][33];
    const int tx = threadIdx.x, ty = threadIdx.y;   // block 32x8
    const int gx = blockIdx.x * 32;                 // N dim
    const int gy = blockIdx.y * 32;                 // K dim
    #pragma unroll
    for (int i = 0; i < 4; ++i)
        t[ty + i*8][tx] = W[(size_t)(gy + ty + i*8) * N + gx + tx];
    __syncthreads();
    #pragma unroll
    for (int i = 0; i < 4; ++i)
        Wt[(size_t)(gx + ty + i*8) * K + gy + tx] = f2bf(t[tx][ty + i*8]);
}

// ---------- f32 -> bf16 cast (row-major copy), 4 elems/thread ----------
__global__ __launch_bounds__(256) void cast_bf16(
    const float* __restrict__ W, u16* __restrict__ o, int n4)
{
    const int i = blockIdx.x * 256 + threadIdx.x;
    if (i < n4) {
        float4 v = reinterpret_cast<const float4*>(W)[i];
        union { u16 u[4]; uint2 q; } r;
        r.u[0]=f2bf(v.x); r.u[1]=f2bf(v.y); r.u[2]=f2bf(v.z); r.u[3]=f2bf(v.w);
        reinterpret_cast<uint2*>(o)[i] = r.q;
    }
}

// ---------- fused bias: bc[n] = sum_j pb[j]*Wf[j][n] + bf[n]  (wave/output) ----------
__global__ __launch_bounds__(256) void fuse_bias(
    const float* __restrict__ pb, const float* __restrict__ Wf,
    const float* __restrict__ bf, float* __restrict__ bc)
{
    const int n = blockIdx.x * 4 + (threadIdx.x >> 6);
    const int lane = threadIdx.x & 63;
    float s = 0.f;
    #pragma unroll
    for (int it = 0; it < 12; ++it) {
        const int j = it*64 + lane;
        s += pb[j] * Wf[(size_t)j * 768 + n];
    }
    #pragma unroll
    for (int o = 32; o > 0; o >>= 1) s += __shfl_xor(s, o);
    if (lane == 0) bc[n] = s + bf[n];
}

// ---------- LayerNorm (wave per row, 4 rows/block), writes bf16 ----------
template<int MODE>
__global__ __launch_bounds__(256) void ln_kernel(
    const float* __restrict__ xp, const u16* __restrict__ xt2,
    const float* __restrict__ w, const float* __restrict__ b,
    u16* __restrict__ out, int nrows)
{
    const int row = blockIdx.x * 4 + (threadIdx.x >> 6);
    if (row >= nrows) return;
    const int lane = threadIdx.x & 63;
    float vals[12];
    if constexpr (MODE == 0) {
        const float* src = xp + (size_t)(row + row/3136 + 1) * 768;
        #pragma unroll
        for (int j = 0; j < 3; ++j) {
            float4 v = reinterpret_cast<const float4*>(src)[j*64 + lane];
            vals[j*4+0]=v.x; vals[j*4+1]=v.y; vals[j*4+2]=v.z; vals[j*4+3]=v.w;
        }
    } else {
        const int bt = row / 197;
        const int p  = row - bt * 197;
        const int b0 = bt >> 4, tt = bt & 15;
        if (p == 0) {
            const float* src = xp + (size_t)b0 * 3137 * 768;
            #pragma unroll
            for (int j = 0; j < 3; ++j) {
                float4 v = reinterpret_cast<const float4*>(src)[j*64 + lane];
                vals[j*4+0]=v.x; vals[j*4+1]=v.y; vals[j*4+2]=v.z; vals[j*4+3]=v.w;
            }
        } else {
            const u16* src = xt2 + (size_t)(b0*3136 + (p-1)*16 + tt) * 768;
            #pragma unroll
            for (int j = 0; j < 3; ++j) {
                uint2 q = reinterpret_cast<const uint2*>(src)[j*64 + lane];
                vals[j*4+0] = bf2f((u16)(q.x & 0xFFFF));
                vals[j*4+1] = bf2f((u16)(q.x >> 16));
                vals[j*4+2] = bf2f((u16)(q.y & 0xFFFF));
                vals[j*4+3] = bf2f((u16)(q.y >> 16));
            }
        }
    }
    float s = 0.f, ss = 0.f;
    #pragma unroll
    for (int e = 0; e < 12; ++e) { s += vals[e]; ss += vals[e]*vals[e]; }
    #pragma unroll
    for (int o = 32; o > 0; o >>= 1) { s += __shfl_xor(s, o); ss += __shfl_xor(ss, o); }
    const float mean = s * (1.f/768.f);
    const float var  = ss * (1.f/768.f) - mean*mean;
    const float rstd = rsqrtf(var + 1e-5f);
    #pragma unroll
    for (int j = 0; j < 3; ++j) {
        const int c4 = (j*64 + lane) * 4;
        union { u16 u[4]; uint2 q; } o;
        #pragma unroll
        for (int e = 0; e < 4; ++e)
            o.u[e] = f2bf((vals[j*4+e] - mean)*rstd*w[c4+e] + b[c4+e]);
        *reinterpret_cast<uint2*>(&out[(size_t)row*768 + c4]) = o.q;
    }
}

// ---------- combine: x_new = concat residuals (f32 -> d_out), then LN(n2) bf16 ----------
__global__ __launch_bounds__(256) void combine_ln2(
    const float* __restrict__ xp, const u16* __restrict__ xt2,
    const u16* __restrict__ rsb, const float* __restrict__ w, const float* __restrict__ b,
    float* __restrict__ xnew, u16* __restrict__ ln2, int nrows)
{
    const int row = blockIdx.x * 4 + (threadIdx.x >> 6);
    if (row >= nrows) return;
    const int lane = threadIdx.x & 63;
    const int b0 = row / 3137;
    const int j  = row - b0 * 3137;
    float vals[12];
    if (j == 0) {       // cls row: x[b,0] + mean_t rs[(b,t) seq, token 0]
        #pragma unroll
        for (int e = 0; e < 12; ++e) {
            const int c = e*64 + lane;
            float acc = 0.f;
            for (int t = 0; t < 16; ++t)
                acc += bf2f(rsb[(size_t)(b0*16 + t) * 197 * 768 + c]);
            vals[e] = xp[(size_t)row*768 + c] + acc * (1.f/16.f);
        }
    } else {
        const int n_idx = j - 1;
        const int hw = n_idx >> 4, tt = n_idx & 15;
        const u16* a  = xt2 + (size_t)(b0*3136 + n_idx) * 768;
        const u16* r2 = rsb + (size_t)((b0*16 + tt)*197 + 1 + hw) * 768;
        #pragma unroll
        for (int e = 0; e < 12; ++e) {
            const int c = e*64 + lane;
            vals[e] = bf2f(a[c]) + bf2f(r2[c]);
        }
    }
    float s = 0.f, ss = 0.f;
    #pragma unroll
    for (int e = 0; e < 12; ++e) { s += vals[e]; ss += vals[e]*vals[e]; }
    #pragma unroll
    for (int o = 32; o > 0; o >>= 1) { s += __shfl_xor(s, o); ss += __shfl_xor(ss, o); }
    const float mean = s * (1.f/768.f);
    const float var  = ss * (1.f/768.f) - mean*mean;
    const float rstd = rsqrtf(var + 1e-5f);
    #pragma unroll
    for (int e = 0; e < 12; ++e) {
        const int c = e*64 + lane;
        xnew[(size_t)row*768 + c] = vals[e];
        ln2[(size_t)row*768 + c]  = f2bf((vals[e] - mean)*rstd*w[c] + b[c]);
    }
}

// ============================================================================
// GEMM: C[M,N] = act(A[M,K]bf16 @ B + bias (+resid)) — round-0 proven base +
//  (a) DOUBLE-BUFFERED single-__syncthreads K-loop: stage k+1 into buf^1
//      before computing buf; compiler's vmcnt drain at the barrier lands
//      AFTER ~600 cy of MFMA instead of immediately after DMA issue.
//      LDS 32 KB (2 x {A 8KB + B 8KB}). Zero hand waits -> zero race surface.
//  (b) XCD-aware bijective block remap (m204): consecutive same-A-panel
//      tiles land on one XCD's private L2 -> A re-fetch drops.
// 128x128 tile, BK=32, 4 waves of 4x4 16x16x32 MFMAs, XOR-swizzled LDS.
// ============================================================================
template<int RESID, bool BIAS, bool GELU_ACT, bool OUTF, bool OUTB, bool MASKM>
__global__ __launch_bounds__(256) void gemm_bt(
    const u16* __restrict__ A, const u16* __restrict__ Bt,
    const float* __restrict__ bias, const float* __restrict__ resid,
    float* __restrict__ Cf, u16* __restrict__ Cb,
    int N, int K, int lda, int ldb, int Mvalid)
{
    __shared__ __attribute__((aligned(16))) u16 smem[4*128*32];   // 32 KB
    const int tid  = threadIdx.x;
    const int wave = tid >> 6;
    const int lane = tid & 63;
    const int m15  = lane & 15;
    const int quad = lane >> 4;
    const int wm = wave >> 1, wn = wave & 1;

    // XCD-aware bijective remap of the linear block id (m204 formula)
    const int gx = (int)gridDim.x;
    const int nwg = gx * (int)gridDim.y;
    int lid = (int)blockIdx.y * gx + (int)blockIdx.x;
    {
        const int q = nwg >> 3, r = nwg & 7;
        const int c = lid & 7, idx = lid >> 3;
        lid = (c < r ? c*(q+1) : r*(q+1) + (c-r)*q) + idx;
    }
    const int bx = lid % gx;
    const int by = lid / gx;
    const long m0 = (long)by * 128;   // M-tile (slow dim)
    const long n0 = (long)bx * 128;   // N-tile (fast dim -> A reuse)

    // staging slots: slot s holds global chunk (row=s>>2, kc=(s&3)^((s>>3)&3))
    const int s0 = wave*128 + lane;
    const int s1 = s0 + 64;
    const int kc0 = (s0 & 3) ^ ((s0 >> 3) & 3);
    const int kc1 = (s1 & 3) ^ ((s1 >> 3) & 3);
    const u16* Ag0 = A  + (size_t)(m0 + (s0 >> 2)) * lda + kc0 * 8;
    const u16* Ag1 = A  + (size_t)(m0 + (s1 >> 2)) * lda + kc1 * 8;
    const u16* Bg0 = Bt + (size_t)(n0 + (s0 >> 2)) * ldb + kc0 * 8;
    const u16* Bg1 = Bt + (size_t)(n0 + (s1 >> 2)) * ldb + kc1 * 8;

    // reader swizzle: row-invariant across fragments (rows differ by mult of 16)
    const int swz = (quad ^ ((m15 >> 1) & 3)) * 8;

    floatx4 acc[4][4];
    #pragma unroll
    for (int i = 0; i < 4; ++i)
        #pragma unroll
        for (int j = 0; j < 4; ++j) acc[i][j] = fzero();

    // buffer d: A at smem + d*8192, B at smem + d*8192 + 4096 (u16 units)
    auto stg = [&](int k0, int dn) {
        u16* base = smem + dn*8192;
        async_ld16(Ag0 + k0, base + (wave*2+0)*512);
        async_ld16(Ag1 + k0, base + (wave*2+1)*512);
        async_ld16(Bg0 + k0, base + 4096 + (wave*2+0)*512);
        async_ld16(Bg1 + k0, base + 4096 + (wave*2+1)*512);
    };
    auto comp = [&](int dn) {
        const u16* base = smem + dn*8192;
        bf16x8 af[4], bfr[4];
        #pragma unroll
        for (int i = 0; i < 4; ++i)
            af[i] = *reinterpret_cast<const bf16x8*>(&base[(wm*64 + i*16 + m15)*32 + swz]);
        #pragma unroll
        for (int j = 0; j < 4; ++j)
            bfr[j] = *reinterpret_cast<const bf16x8*>(&base[4096 + (wn*64 + j*16 + m15)*32 + swz]);
        #pragma unroll
        for (int i = 0; i < 4; ++i)
            #pragma unroll
            for (int j = 0; j < 4; ++j)
                acc[i][j] = mfma32(af[i], bfr[j], acc[i][j]);
    };

    const int NK = K >> 5;         // K/32; always even here (24 or 48)
    stg(0, 0);
    __syncthreads();               // buf0 ready (vmcnt drained by barrier)
    for (int k = 0; k < NK; k += 2) {
        stg((k+1) << 5, 1);        // k+1 < NK always (NK even)
        comp(0);
        __syncthreads();           // stage(k+1) landed; reads of buf0 done
        if (k + 2 < NK) stg((k+2) << 5, 0);
        comp(1);
        __syncthreads();           // stage(k+2) landed; reads of buf1 done
    }

    // epilogue: D row=(quad*4+r), col=lane&15 within each 16x16 tile
    float bv[4];
    #pragma unroll
    for (int j = 0; j < 4; ++j)
        bv[j] = BIAS ? bias[n0 + wn*64 + j*16 + m15] : 0.f;

    if constexpr (OUTB) {
        // stage through LDS, write 128B-line-aligned uint4
        u16* cbuf = smem + wave * 2048;        // 4 KB per wave
        #pragma unroll
        for (int p = 0; p < 2; ++p) {
            __syncthreads();                   // cbuf region free
            #pragma unroll
            for (int ii = 0; ii < 2; ++ii) {
                const int i = p*2 + ii;
                #pragma unroll
                for (int j = 0; j < 4; ++j) {
                    #pragma unroll
                    for (int r = 0; r < 4; ++r) {
                        const long row = m0 + wm*64 + i*16 + quad*4 + r;
                        float v = acc[i][j][r] + bv[j];
                        if constexpr (RESID == 1)
                            v += resid[(size_t)row * N + (n0 + wn*64 + j*16 + m15)];
                        if constexpr (RESID == 2)
                            v += resid[(size_t)(row + row/3136 + 1) * 768 + (n0 + wn*64 + j*16 + m15)];
                        if constexpr (GELU_ACT)
                            v = 0.5f * v * (1.f + erff(v * 0.70710678118f));
                        cbuf[(ii*16 + quad*4 + r)*64 + j*16 + m15] = f2bf(v);
                    }
                }
            }
            __syncthreads();                   // cbuf visible to whole wave set
            #pragma unroll
            for (int it = 0; it < 4; ++it) {
                const int lr = (lane >> 3) + it*8;
                const int cc = lane & 7;
                const uint4 val = *reinterpret_cast<const uint4*>(&cbuf[lr*64 + cc*8]);
                const long grow = m0 + wm*64 + p*32 + lr;
                *reinterpret_cast<uint4*>(&Cb[(size_t)grow * N + n0 + wn*64 + cc*8]) = val;
            }
        }
    } else {
        #pragma unroll
        for (int j = 0; j < 4; ++j) {
            const long col = n0 + wn*64 + j*16 + m15;
            #pragma unroll
            for (int i = 0; i < 4; ++i) {
                const long rowb = m0 + wm*64 + i*16 + quad*4;
                #pragma unroll
                for (int r = 0; r < 4; ++r) {
                    const long row = rowb + r;
                    if constexpr (MASKM) { if (row >= Mvalid) continue; }
                    float v = acc[i][j][r] + bv[j];
                    if constexpr (RESID == 1) v += resid[(size_t)row * N + col];
                    if constexpr (RESID == 2) v += resid[(size_t)(row + row/3136 + 1) * 768 + col];
                    if constexpr (GELU_ACT)   v = 0.5f * v * (1.f + erff(v * 0.70710678118f));
                    if constexpr (OUTF) Cf[(size_t)row * N + col] = v;
                }
            }
        }
    }
}

// ---------- fused attention (flash-style), one wave per (seq, head, q-tile) ----------
template<int S, int NQ, int NIT>
__global__ __launch_bounds__(256) void attn_kernel(
    const u16* __restrict__ qkv, u16* __restrict__ out, int ntask)
{
    __shared__ __attribute__((aligned(16))) u16 P_lds[4][16*32];
    const int wave = threadIdx.x >> 6;
    const int lane = threadIdx.x & 63;
    const int task = blockIdx.x * 4 + wave;
    if (task >= ntask) return;
    const int seq  = task / (12 * NQ);
    const int rem  = task - seq * (12 * NQ);
    const int head = rem / NQ;
    const int qt   = rem - head * NQ;
    const int m15  = lane & 15;
    const int quad = lane >> 4;
    const size_t base = (size_t)seq * S;

    const u16* qp = qkv + (base + qt*16 + m15) * 2304 + head*64 + quad*8;
    const bf16x8 Qf0 = *reinterpret_cast<const bf16x8*>(qp);
    const bf16x8 Qf1 = *reinterpret_cast<const bf16x8*>(qp + 32);

    floatx4 Oacc[4];
    #pragma unroll
    for (int c = 0; c < 4; ++c) Oacc[c] = fzero();
    float mrun = -__builtin_inff();
    float lrun = 0.f;
    u16* P = &P_lds[wave][0];

    for (int it = 0; it < NIT; ++it) {
        const int j0 = it * 32;
        floatx4 st[2];
        #pragma unroll
        for (int h2 = 0; h2 < 2; ++h2) {
            const u16* kp = qkv + (base + j0 + h2*16 + m15) * 2304 + 768 + head*64 + quad*8;
            const bf16x8 K0 = *reinterpret_cast<const bf16x8*>(kp);
            const bf16x8 K1 = *reinterpret_cast<const bf16x8*>(kp + 32);
            floatx4 z = fzero();
            z = mfma32(K0, Qf0, z);
            st[h2] = mfma32(K1, Qf1, z);
        }
        float sc[8];
        #pragma unroll
        for (int h2 = 0; h2 < 2; ++h2)
            #pragma unroll
            for (int r = 0; r < 4; ++r) {
                const int jj = j0 + h2*16 + quad*4 + r;
                sc[h2*4+r] = (jj < S) ? st[h2][r] * 0.125f : -__builtin_inff();
            }
        float tmax = sc[0];
        #pragma unroll
        for (int k = 1; k < 8; ++k) tmax = fmaxf(tmax, sc[k]);
        tmax = fmaxf(tmax, __shfl_xor(tmax, 16));
        tmax = fmaxf(tmax, __shfl_xor(tmax, 32));
        const float mnew = fmaxf(mrun, tmax);
        float p[8], tsum = 0.f;
        #pragma unroll
        for (int k = 0; k < 8; ++k) { p[k] = __expf(sc[k] - mnew); tsum += p[k]; }
        tsum += __shfl_xor(tsum, 16);
        tsum += __shfl_xor(tsum, 32);
        const float alpha = __expf(mrun - mnew);
        lrun = lrun * alpha + tsum;
        mrun = mnew;
        #pragma unroll
        for (int r = 0; r < 4; ++r) {             // rescale O rows (row = quad*4+r)
            const float ar = __shfl(alpha, quad*4 + r);
            #pragma unroll
            for (int c = 0; c < 4; ++c) Oacc[c][r] *= ar;
        }
        // P round-trip through LDS: C-layout -> A-operand layout
        #pragma unroll
        for (int h2 = 0; h2 < 2; ++h2)
            #pragma unroll
            for (int r = 0; r < 4; ++r)
                P[m15*32 + h2*16 + quad*4 + r] = f2bf(p[h2*4+r]);
        const bf16x8 Pf = *reinterpret_cast<const bf16x8*>(&P[m15*32 + quad*8]);
        #pragma unroll
        for (int c = 0; c < 4; ++c) {             // V in B-operand layout (scattered u16)
            union { u16 u[8]; bf16x8 v; } vf;
            #pragma unroll
            for (int jj2 = 0; jj2 < 8; ++jj2)
                vf.u[jj2] = qkv[(base + j0 + quad*8 + jj2) * 2304 + 1536 + head*64 + c*16 + m15];
            Oacc[c] = mfma32(Pf, vf.v, Oacc[c]);
        }
    }
    const float linv_self = 1.f / lrun;
    #pragma unroll
    for (int r = 0; r < 4; ++r) {
        const int prow = qt*16 + quad*4 + r;
        const float linv = __shfl(linv_self, quad*4 + r);
        if (prow < S) {
            u16* op = out + (base + prow) * 768 + head*64 + m15;
            #pragma unroll
            for (int c = 0; c < 4; ++c) op[c*16] = f2bf(Oacc[c][r] * linv);
        }
    }
}

// ---------- host ----------
extern "C" void kernel_launch(void* const* d_in, const int* in_sizes, int n_in,
                              void* d_out, int out_size, void* d_ws, size_t ws_size,
                              hipStream_t stream)
{
    (void)in_sizes; (void)n_in; (void)out_size; (void)ws_size;
    const float* x        = (const float*)d_in[0];
    const float* tn1_w    = (const float*)d_in[1];
    const float* tn1_b    = (const float*)d_in[2];
    const float* t_qkv_w  = (const float*)d_in[3];
    const float* t_proj_w = (const float*)d_in[4];
    const float* t_proj_b = (const float*)d_in[5];
    const float* tfc_w    = (const float*)d_in[6];
    const float* tfc_b    = (const float*)d_in[7];
    const float* n1_w     = (const float*)d_in[8];
    const float* n1_b     = (const float*)d_in[9];
    const float* s_qkv_w  = (const float*)d_in[10];
    const float* s_proj_w = (const float*)d_in[11];
    const float* s_proj_b = (const float*)d_in[12];
    const float* n2_w     = (const float*)d_in[13];
    const float* n2_b     = (const float*)d_in[14];
    const float* fc1_w    = (const float*)d_in[15];
    const float* fc1_b    = (const float*)d_in[16];
    const float* fc2_w    = (const float*)d_in[17];
    const float* fc2_b    = (const float*)d_in[18];
    float* out = (float*)d_out;

    char* ws = (char*)d_ws;
    size_t off = 0;
    auto alloc = [&](size_t bytes) -> void* {
        void* p = ws + off;
        off += (bytes + 255) & ~(size_t)255;
        return p;
    };
    // weights (bf16)                                  total ~21.3 MB
    u16* wt_tqkv  = (u16*)alloc((size_t)768*2304*2);   // [N][K] transposed
    u16* tproj_rm = (u16*)alloc((size_t)768*768*2);    // t_proj row-major cast
    u16* wt_tfc   = (u16*)alloc((size_t)768*768*2);    // [N][K] transposed
    u16* wt_comb  = (u16*)alloc((size_t)768*768*2);    // (tproj@tfc)^T bf16
    float* bcomb  = (float*)alloc((size_t)768*4);      // tproj_b@tfc + tfc_b
    u16* wt_sqkv  = (u16*)alloc((size_t)768*2304*2);
    u16* wt_sproj = (u16*)alloc((size_t)768*768*2);
    u16* wt_fc1   = (u16*)alloc((size_t)768*3072*2);
    u16* wt_fc2   = (u16*)alloc((size_t)3072*768*2);
    // activation slots (aliased lifetimes)            total ~233 MB
    u16* slotA = (u16*)alloc((size_t)25280*2304*2);  // qkv_t / qkv_s / h1 halves
    u16* slotB = (u16*)alloc((size_t)25216*768*2);   // xt2 bf16
    u16* slotD = (u16*)alloc((size_t)25216*768*2);   // ln_t/attn_t/ln_s/attn_s/ln2
    u16* slotE = (u16*)alloc((size_t)25216*768*2);   // rs bf16

    dim3 tb(32, 8);
    transpose_w<<<dim3(72, 24), tb, 0, stream>>>(t_qkv_w,  wt_tqkv,  768, 2304);
    transpose_w<<<dim3(24, 24), tb, 0, stream>>>(tfc_w,    wt_tfc,   768, 768);
    transpose_w<<<dim3(72, 24), tb, 0, stream>>>(s_qkv_w,  wt_sqkv,  768, 2304);
    transpose_w<<<dim3(24, 24), tb, 0, stream>>>(s_proj_w, wt_sproj, 768, 768);
    transpose_w<<<dim3(96, 24), tb, 0, stream>>>(fc1_w,    wt_fc1,   768, 3072);
    transpose_w<<<dim3(24, 96), tb, 0, stream>>>(fc2_w,    wt_fc2,   3072, 768);
    cast_bf16<<<576, 256, 0, stream>>>(t_proj_w, tproj_rm, 768*768/4);

    // combined weight: Wc^T[n][k] = sum_j wt_tfc[n][j] * tproj_rm[k][j]
    // (= (tproj_w @ tfc_w) transposed) + combined bias
    gemm_bt<0,false,false,false,true,false><<<dim3(6,6), 256, 0, stream>>>(
        wt_tfc, tproj_rm, nullptr, nullptr, nullptr, wt_comb, 768, 768, 768, 768, 0);
    fuse_bias<<<192, 256, 0, stream>>>(t_proj_b, tfc_w, tfc_b, bcomb);

    u16* lnT  = slotD;
    u16* qkvT = slotA;
    ln_kernel<0><<<25088/4, 256, 0, stream>>>(x, nullptr, tn1_w, tn1_b, lnT, 25088);
    gemm_bt<0,false,false,false,true,false><<<dim3(18,196), 256, 0, stream>>>(
        lnT, wt_tqkv, nullptr, nullptr, nullptr, qkvT, 2304, 768, 768, 768, 0);

    u16* attnT = slotD;
    attn_kernel<16,1,1><<<18816/4, 256, 0, stream>>>(qkvT, attnT, 18816);

    // fused (proj @ tfc): xt2 = attnT @ Wcomb + bcomb + x-residual (skip-cls)
    u16* xt2 = slotB;
    gemm_bt<2,true,false,false,true,false><<<dim3(6,196), 256, 0, stream>>>(
        attnT, wt_comb, bcomb, x, nullptr, xt2, 768, 768, 768, 768, 0);

    u16* lnS = slotD;
    ln_kernel<1><<<25216/4, 256, 0, stream>>>(x, xt2, n1_w, n1_b, lnS, 25216);

    u16* qkvS = slotA;
    gemm_bt<0,false,false,false,true,false><<<dim3(18,197), 256, 0, stream>>>(
        lnS, wt_sqkv, nullptr, nullptr, nullptr, qkvS, 2304, 768, 768, 768, 0);

    u16* attnS = slotD;
    attn_kernel<197,13,7><<<19968/4, 256, 0, stream>>>(qkvS, attnS, 19968);

    u16* rsb = slotE;
    gemm_bt<0,true,false,false,true,false><<<dim3(6,197), 256, 0, stream>>>(
        attnS, wt_sproj, s_proj_b, nullptr, nullptr, rsb, 768, 768, 768, 768, 0);

    float* xnew = out;                // x_new lives in d_out
    u16* ln2 = slotD;
    combine_ln2<<<25096/4, 256, 0, stream>>>(x, xt2, rsb, n2_w, n2_b, xnew, ln2, 25096);

    // MLP split into two hidden halves (h1 fits in slotA)
    u16* h1 = slotA;
    for (int half = 0; half < 2; ++half) {
        const u16* w1h = wt_fc1 + (size_t)half * 1536 * 768;   // rows [N-half][768]
        const float* b1h = fc1_b + half * 1536;
        gemm_bt<0,true,true,false,true,false><<<dim3(12,197), 256, 0, stream>>>(
            ln2, w1h, b1h, nullptr, nullptr, h1, 1536, 768, 768, 768, 0);
        const u16* w2h = wt_fc2 + (size_t)half * 1536;         // [768][3072] K-offset
        if (half == 0)
            gemm_bt<1,true,false,true,false,true><<<dim3(6,197), 256, 0, stream>>>(
                h1, w2h, fc2_b, out, out, nullptr, 768, 1536, 1536, 3072, 25096);
        else
            gemm_bt<1,false,false,true,false,true><<<dim3(6,197), 256, 0, stream>>>(
                h1, w2h, nullptr, out, out, nullptr, 768, 1536, 1536, 3072, 25096);
    }
}